// Round 9
// baseline (1387.157 us; speedup 1.0000x reference)
//
#include <hip/hip_runtime.h>
#include <math.h>

#define NN 100000
#define NE 3200000
#define NG 512
#define NBK 782            // dst buckets: ceil(NN/128), bucket = dst>>7
#define EBLK 782           // edge blocks: ceil(NE/4096)

typedef __attribute__((ext_vector_type(8))) short short8;
typedef __attribute__((ext_vector_type(4))) float f32x4;
typedef __attribute__((ext_vector_type(2))) float f32x2;

// ---------------- bf16 / fp8 helpers ----------------
__device__ __forceinline__ float bf2f(unsigned short h){
  return __uint_as_float(((unsigned int)h) << 16);
}
__device__ __forceinline__ unsigned short f2bf(float f){
  unsigned int u = __float_as_uint(f);
  unsigned int r = (u + 0x7fffu + ((u >> 16) & 1u)) >> 16;   // RNE
  return (unsigned short)r;
}
__device__ __forceinline__ void unpack16(uint4 v, float* f){
  f32x2 p;
  p = __builtin_amdgcn_cvt_pk_f32_fp8(v.x, 0); f[0]=p[0];  f[1]=p[1];
  p = __builtin_amdgcn_cvt_pk_f32_fp8(v.x, 1); f[2]=p[0];  f[3]=p[1];
  p = __builtin_amdgcn_cvt_pk_f32_fp8(v.y, 0); f[4]=p[0];  f[5]=p[1];
  p = __builtin_amdgcn_cvt_pk_f32_fp8(v.y, 1); f[6]=p[0];  f[7]=p[1];
  p = __builtin_amdgcn_cvt_pk_f32_fp8(v.z, 0); f[8]=p[0];  f[9]=p[1];
  p = __builtin_amdgcn_cvt_pk_f32_fp8(v.z, 1); f[10]=p[0]; f[11]=p[1];
  p = __builtin_amdgcn_cvt_pk_f32_fp8(v.w, 0); f[12]=p[0]; f[13]=p[1];
  p = __builtin_amdgcn_cvt_pk_f32_fp8(v.w, 1); f[14]=p[0]; f[15]=p[1];
}
__device__ __forceinline__ unsigned char f2fp8(float v){
  int p = __builtin_amdgcn_cvt_pk_fp8_f32(v, v, 0, 0);
  return (unsigned char)p;
}

// ---------------- scan-based multi-split CSR build ----------------
// A) per-edge-block bucket histogram -> cnt[blk*NBK+b] (coalesced) + global btot
__global__ __launch_bounds__(256) void hist2_k(const int* __restrict__ ei,
    int* __restrict__ cnt, int* __restrict__ btot){
  __shared__ int lh[NBK];
  int t = threadIdx.x, b = blockIdx.x;
  for (int i=t; i<NBK; i+=256) lh[i] = 0;
  __syncthreads();
  int base = b*4096;
  #pragma unroll
  for (int u=0; u<16; u++){
    int e = base + u*256 + t;
    if (e < NE) atomicAdd(&lh[ei[NE + e] >> 7], 1);
  }
  __syncthreads();
  for (int i=t; i<NBK; i+=256){
    int v = lh[i];
    cnt[b*NBK + i] = v;
    if (v) atomicAdd(&btot[i], v);
  }
}
// B) scan of bucket totals -> bptr (exclusive)
__global__ void bscan2_k(const int* __restrict__ btot, int* __restrict__ bptr){
  __shared__ int sc[1024];
  int t = threadIdx.x;
  int v = (t < NBK) ? btot[t] : 0;
  sc[t] = v; __syncthreads();
  for (int off=1; off<1024; off<<=1){
    int u = (t>=off) ? sc[t-off] : 0;
    __syncthreads(); sc[t] += u; __syncthreads();
  }
  if (t < NBK) bptr[t] = sc[t] - v;
  if (t == 1023) bptr[NBK] = sc[1023];
}
// C) per-bucket exclusive prefix over edge-blocks: cnt[blk][b] <- bptr[b]+prefix
__global__ __launch_bounds__(256) void bkpfx_k(int* __restrict__ cnt, const int* __restrict__ bptr){
  __shared__ int sc[256];
  int b = blockIdx.x, t = threadIdx.x;
  int carry = bptr[b];
  for (int base=0; base<EBLK; base+=256){
    int blk = base + t;
    int v = (blk < EBLK) ? cnt[blk*NBK + b] : 0;
    sc[t] = v; __syncthreads();
    for (int off=1; off<256; off<<=1){
      int u = (t>=off) ? sc[t-off] : 0;
      __syncthreads(); sc[t] += u; __syncthreads();
    }
    if (blk < EBLK) cnt[blk*NBK + b] = carry + sc[t] - v;   // exclusive + base
    carry += sc[255];
    __syncthreads();
  }
}
// D) placement scatter: pos = off[blk][bucket] + LDS rank (contention only on LDS)
__global__ __launch_bounds__(256) void scat2_k(const int* __restrict__ ei,
    const int* __restrict__ cnt, uint2* __restrict__ ebuf){
  __shared__ int lh[NBK];
  __shared__ int lo[NBK];
  int t = threadIdx.x, b = blockIdx.x;
  for (int i=t; i<NBK; i+=256){ lh[i] = 0; lo[i] = cnt[b*NBK + i]; }
  __syncthreads();
  int base = b*4096;
  #pragma unroll
  for (int u=0; u<16; u++){
    int e = base + u*256 + t;
    if (e < NE){
      int s = ei[e], d = ei[NE + e];
      int bk = d >> 7;
      int r = atomicAdd(&lh[bk], 1);
      ebuf[lo[bk] + r] = make_uint2((unsigned)s, (unsigned)d);
    }
  }
}
// E) fused per-bucket CSR finalize: deg count + in-bucket scan -> rp/dinv, then col fill.
// Buckets are contiguous in ebuf, so rp[node] = bptr[b] + local exclusive sum. One ebuf read
// (second pass is L2-hot). Replaces bdeg + scanA/B/C + ccol.
__global__ __launch_bounds__(256) void bcsr_k(const uint2* __restrict__ ebuf,
    const int* __restrict__ bptr, int* __restrict__ rp, float* __restrict__ dinv,
    int* __restrict__ col){
  __shared__ int cnt[128];
  __shared__ int off[128];
  __shared__ int sc[128];
  int b = blockIdx.x, t = threadIdx.x;
  int nbase = b << 7;
  int beg = bptr[b], end = bptr[b+1];
  if (t < 128) cnt[t] = 0;
  __syncthreads();
  for (int e = beg + t; e < end; e += 256)
    atomicAdd(&cnt[(int)ebuf[e].y - nbase], 1);
  __syncthreads();
  int v = (t < 128) ? cnt[t] : 0;
  if (t < 128) sc[t] = v;
  __syncthreads();
  for (int o2=1; o2<128; o2<<=1){
    int u = (t < 128 && t >= o2) ? sc[t-o2] : 0;
    __syncthreads();
    if (t < 128) sc[t] += u;
    __syncthreads();
  }
  if (t < 128){
    int node = nbase + t;
    if (node < NN){
      int ex = beg + sc[t] - v;          // exclusive in-bucket + bucket base
      rp[node] = ex;
      off[t] = ex;
      dinv[node] = rsqrtf((float)(v + 1)); // +1 self loop
      cnt[t] = 0;                          // reuse as cursor
    }
  }
  if (b == ((NN-1) >> 7) && t == 0) rp[NN] = end;
  __syncthreads();
  for (int e = beg + t; e < end; e += 256){
    uint2 sd = ebuf[e];
    int li = (int)sd.y - nbase;
    int pos = off[li] + atomicAdd(&cnt[li], 1);
    col[pos] = (int)sd.x;
  }
}

// fp32 -> fp8 (4 values/thread)
__global__ void f2q_k(const float* __restrict__ in, unsigned char* __restrict__ out, int n4){
  int i = blockIdx.x*256 + threadIdx.x;
  if (i < n4){
    float4 v = ((const float4*)in)[i];
    int p = __builtin_amdgcn_cvt_pk_fp8_f32(v.x, v.y, 0, 0);
    p = __builtin_amdgcn_cvt_pk_fp8_f32(v.z, v.w, p, 1);
    ((unsigned int*)out)[i] = (unsigned int)p;
  }
}
// all 6 weight swizzles in one launch. blockIdx.y selects config.
__global__ void wswz_all_k(const float* W1, const float* W2, const float* W3,
                           const float* W4, const float* W5, const float* W6,
                           unsigned short* O1, unsigned short* O2, unsigned short* O3,
                           unsigned short* O4, unsigned short* O5, unsigned short* O6){
  int cfg = blockIdx.y;
  int K, N; const float* W; unsigned short* out;
  switch(cfg){
    case 0: K=128; N=256; W=W1; out=O1; break;
    case 1: K=256; N=256; W=W2; out=O2; break;
    case 2: K=256; N=256; W=W3; out=O3; break;
    case 3: K=256; N=128; W=W4; out=O4; break;
    case 4: K=128; N=128; W=W5; out=O5; break;
    default:K=128; N=64;  W=W6; out=O6; break;
  }
  int idx = blockIdx.x*256 + threadIdx.x;
  int total = K*N/8;
  if (idx >= total) return;
  int l = idx & 15;
  int t = idx >> 4; int q = t & 3; t >>= 2;
  int NT = N/16;
  int nt = t % NT, kt = t / NT;
  int kbase = kt*32 + q*8, n = nt*16 + l;
  short8 o;
  #pragma unroll
  for (int j=0;j<8;j++) o[j] = (short)f2bf(W[(size_t)(kbase+j)*N + n]);
  *(short8*)(out + (size_t)idx*8) = o;
}

// ---------------- XCD-sliced fp8 SpMM ----------------
// out[i] = dinv[i]*(sum_nbr in[src] + in[i]) [+bias][relu]
// Each block handles a 64-channel (one cache line) slice, tied to its XCD via
// blockIdx.x & 7 (consecutive blocks round-robin across the 8 XCDs). With SLICES
// slices, 8/SLICES XCDs split the rows of each slice -> per-XCD gather footprint
// = bytes(buffer)/SLICES, concentrating L2 reuse. Mapping is a perf-only heuristic.
template<int C, int SLICES, bool SRC_SCALE, bool RELU, bool HAS_BIAS>
__global__ __launch_bounds__(256) void spmms_k(const unsigned char* __restrict__ in,
    unsigned short* __restrict__ out,
    const int* __restrict__ rp, const int* __restrict__ col,
    const float* __restrict__ dinv, const float* __restrict__ bias)
{
  constexpr int CS  = C / SLICES;       // channels per slice (64)
  constexpr int LPR = CS / 16;          // lanes per row (4)
  constexpr int RPW = 64 / LPR;         // rows per wave (16)
  constexpr int RPB = 4 * RPW;          // rows per block (64)
  constexpr int XPG = 8 / SLICES;       // XCDs per slice
  constexpr int NRB = (NN + RPB - 1) / RPB;
  int bx = blockIdx.x;
  int xcd = bx & 7;
  int slice = xcd % SLICES;
  int part  = xcd / SLICES;
  int rb = (bx >> 3) * XPG + part;
  if (rb >= NRB) return;
  int tid = threadIdx.x;
  int wv = tid >> 6, lane = tid & 63;
  int sub = lane / LPR, li = lane % LPR;
  int row = rb*RPB + wv*RPW + sub;
  if (row >= NN) return;
  int beg = rp[row], end = rp[row+1];
  float di = dinv[row];
  int co = slice*CS + li*16;
  const unsigned char* inb = in + co;
  float acc[16], tmp[16];
  unpack16(*(const uint4*)(inb + (size_t)row*C), acc);   // self loop
  if (SRC_SCALE){
    #pragma unroll
    for (int v=0;v<16;v++) acc[v] *= di;
  }
  int j = beg;
  for (; j+8 <= end; j += 8){
    int s[8]; uint4 v[8]; float wgt[8];
    #pragma unroll
    for (int u=0;u<8;u++) s[u] = col[j+u];
    #pragma unroll
    for (int u=0;u<8;u++) v[u] = *(const uint4*)(inb + (size_t)s[u]*C);
    if (SRC_SCALE){
      #pragma unroll
      for (int u=0;u<8;u++) wgt[u] = dinv[s[u]];
    }
    #pragma unroll
    for (int u=0;u<8;u++){
      unpack16(v[u], tmp);
      float w = SRC_SCALE ? wgt[u] : 1.f;
      #pragma unroll
      for (int vv=0;vv<16;vv++) acc[vv] = fmaf(w, tmp[vv], acc[vv]);
    }
  }
  for (; j < end; j++){
    int ss = col[j];
    uint4 v = *(const uint4*)(inb + (size_t)ss*C);
    float w = SRC_SCALE ? dinv[ss] : 1.f;
    unpack16(v, tmp);
    #pragma unroll
    for (int vv=0;vv<16;vv++) acc[vv] = fmaf(w, tmp[vv], acc[vv]);
  }
  float bb[16];
  if (HAS_BIAS){
    #pragma unroll
    for (int u=0;u<4;u++) *(float4*)&bb[u*4] = *(const float4*)(bias + co + u*4);
  }
  #pragma unroll
  for (int v=0;v<16;v++){
    acc[v] *= di;
    if (HAS_BIAS) acc[v] += bb[v];
    if (RELU) acc[v] = fmaxf(acc[v], 0.f);
  }
  uint4 o0, o1;
  o0.x = (unsigned int)f2bf(acc[0])  | ((unsigned int)f2bf(acc[1])<<16);
  o0.y = (unsigned int)f2bf(acc[2])  | ((unsigned int)f2bf(acc[3])<<16);
  o0.z = (unsigned int)f2bf(acc[4])  | ((unsigned int)f2bf(acc[5])<<16);
  o0.w = (unsigned int)f2bf(acc[6])  | ((unsigned int)f2bf(acc[7])<<16);
  o1.x = (unsigned int)f2bf(acc[8])  | ((unsigned int)f2bf(acc[9])<<16);
  o1.y = (unsigned int)f2bf(acc[10]) | ((unsigned int)f2bf(acc[11])<<16);
  o1.z = (unsigned int)f2bf(acc[12]) | ((unsigned int)f2bf(acc[13])<<16);
  o1.w = (unsigned int)f2bf(acc[14]) | ((unsigned int)f2bf(acc[15])<<16);
  unsigned short* op = out + (size_t)row*C + co;
  *(uint4*)op = o0;
  *(uint4*)(op + 8) = o1;
}

// ---------------- MFMA bf16 GEMM with LDS-staged B (double buffer) ----------------
// C[M,N] = A[M,K] @ W[K,N], 128 rows/block (2 row-tiles/wave).
// EPI=0: +bias[n], relu, bf16 out.  EPI=1: *dinv[row], fp8 out (for gather).
template<int K, int N, int EPI>
__global__ __launch_bounds__(256) void mgemm_k(const unsigned short* __restrict__ A,
    const unsigned short* __restrict__ Bsw,
    const float* __restrict__ aux, unsigned short* __restrict__ Cb,
    unsigned char* __restrict__ Cq, int M)
{
  constexpr int NT = N/16, KT = K/32;
  __shared__ short8 Bl[2][NT*64];         // one kt-chunk = NT*64 frags = N*64 bytes
  int tid = threadIdx.x;
  int w = tid >> 6, lane = tid & 63;
  int l = lane & 15, q = lane >> 4;
  int rb = blockIdx.x*128 + w*32;
  int r0 = min(rb + l, M-1);
  int r1 = min(rb + 16 + l, M-1);
  f32x4 acc0[NT], acc1[NT];
  #pragma unroll
  for (int nt=0; nt<NT; nt++){ acc0[nt] = (f32x4){0,0,0,0}; acc1[nt] = (f32x4){0,0,0,0}; }
  const unsigned short* ap0 = A + (size_t)r0*K + q*8;
  const unsigned short* ap1 = A + (size_t)r1*K + q*8;
  const short8* bsrc = (const short8*)Bsw;
  #pragma unroll
  for (int i=0;i<NT/4;i++) Bl[0][i*256 + tid] = bsrc[i*256 + tid];
  for (int kt=0; kt<KT; kt++){
    __syncthreads();
    if (kt+1 < KT){
      const short8* s = bsrc + (size_t)(kt+1)*NT*64;
      #pragma unroll
      for (int i=0;i<NT/4;i++) Bl[(kt+1)&1][i*256 + tid] = s[i*256 + tid];
    }
    short8 a0 = *(const short8*)(ap0 + kt*32);
    short8 a1 = *(const short8*)(ap1 + kt*32);
    const short8* bl = &Bl[kt&1][0];
    #pragma unroll
    for (int nt=0; nt<NT; nt++){
      short8 bf = bl[(nt*4 + q)*16 + l];
      acc0[nt] = __builtin_amdgcn_mfma_f32_16x16x32_bf16(a0, bf, acc0[nt], 0,0,0);
      acc1[nt] = __builtin_amdgcn_mfma_f32_16x16x32_bf16(a1, bf, acc1[nt], 0,0,0);
    }
  }
  #pragma unroll
  for (int half=0; half<2; half++){
    int rbb = rb + half*16;
    #pragma unroll
    for (int nt=0; nt<NT; nt++){
      f32x4 a = half ? acc1[nt] : acc0[nt];
      int n = nt*16 + l;
      #pragma unroll
      for (int r=0;r<4;r++){
        int row = rbb + q*4 + r;
        if (row < M){
          float v = a[r];
          if (EPI == 0){
            v = fmaxf(v + aux[n], 0.f);
            Cb[(size_t)row*N + n] = f2bf(v);
          } else {
            v *= aux[row];
            Cq[(size_t)row*N + n] = f2fp8(v);
          }
        }
      }
    }
  }
}

// ---------------- fused mean-pool + linear + (log_)softmax (batch sorted) ----------------
__global__ __launch_bounds__(256) void poolhead_k(const unsigned short* __restrict__ h,
    const int* __restrict__ batch, const float* __restrict__ Wlin,
    const float* __restrict__ blin, float* __restrict__ out)
{
  __shared__ int range[2];
  __shared__ float red[4][64];
  __shared__ float pl[64];
  int g = blockIdx.x;
  if (threadIdx.x < 2){
    int target = g + threadIdx.x;      // lower_bound(batch, target)
    int lo = 0, hi = NN;
    while (lo < hi){ int m = (lo+hi) >> 1; if (batch[m] < target) lo = m+1; else hi = m; }
    range[threadIdx.x] = lo;
  }
  __syncthreads();
  int lo = range[0], hi = range[1];
  int ch = threadIdx.x & 63, rg = threadIdx.x >> 6;
  float s = 0.f;
  for (int r = lo + rg; r < hi; r += 4) s += bf2f(h[(size_t)r*64 + ch]);
  red[rg][ch] = s; __syncthreads();
  if (rg == 0){
    float tot = red[0][ch] + red[1][ch] + red[2][ch] + red[3][ch];
    pl[ch] = tot / fmaxf((float)(hi - lo), 1.f);
  }
  __syncthreads();
  if (threadIdx.x == 0){
    float l[10];
    #pragma unroll
    for (int j=0;j<10;j++) l[j] = blin[j];
    for (int c=0;c<64;c++){
      float p = pl[c];
      #pragma unroll
      for (int j=0;j<10;j++) l[j] = fmaf(p, Wlin[c*10 + j], l[j]);
    }
    float mx = l[0];
    #pragma unroll
    for (int j=1;j<10;j++) mx = fmaxf(mx, l[j]);
    float e[10]; float se = 0.f;
    #pragma unroll
    for (int j=0;j<10;j++){ e[j] = expf(l[j]-mx); se += e[j]; }
    float lse = logf(se);
    #pragma unroll
    for (int j=0;j<10;j++){
      out[g*10 + j]         = l[j] - mx - lse;   // log_softmax
      out[NG*10 + g*10 + j] = e[j] / se;         // softmax
    }
  }
}

// ---------------- launch ----------------
extern "C" void kernel_launch(void* const* d_in, const int* in_sizes, int n_in,
                              void* d_out, int out_size, void* d_ws, size_t ws_size,
                              hipStream_t stream)
{
  const float* x     = (const float*)d_in[0];
  const int*   ei    = (const int*)  d_in[1];
  const int*   batch = (const int*)  d_in[2];
  const float* W1=(const float*)d_in[4],  *b1=(const float*)d_in[5];
  const float* W2=(const float*)d_in[6],  *b2=(const float*)d_in[7];
  const float* W3=(const float*)d_in[8],  *b3=(const float*)d_in[9];
  const float* W4=(const float*)d_in[10], *b4=(const float*)d_in[11];
  const float* W5=(const float*)d_in[12], *b5=(const float*)d_in[13];
  const float* W6=(const float*)d_in[14], *b6=(const float*)d_in[15];
  const float* Wl=(const float*)d_in[16], *bl=(const float*)d_in[17];
  float* out = (float*)d_out;

  char* ws = (char*)d_ws;
  unsigned short* hA  = (unsigned short*)(ws + 0);            // bf16 51,200,000
  unsigned short* hB  = (unsigned short*)(ws + 51200000);     // bf16 51,200,000
  unsigned char*  hQ  = (unsigned char*) (ws + 102400000);    // fp8  25,600,000
  unsigned char*  xq  = (unsigned char*) (ws + 128000000);    // fp8  12,800,000
  int*   col   = (int*)  (ws + 140800000);                    // 12,800,000
  uint2* ebuf  = (uint2*)(ws + 153600000);                    // 25,600,000
  int*   rp    = (int*)  (ws + 179200000);                    // 400,016
  float* dinv  = (float*)(ws + 180000016);                    // 400,000
  unsigned short* W1s = (unsigned short*)(ws + 180400016);    // 65,536
  unsigned short* W2s = (unsigned short*)(ws + 180465552);    // 131,072
  unsigned short* W3s = (unsigned short*)(ws + 180596624);    // 131,072
  unsigned short* W4s = (unsigned short*)(ws + 180727696);    // 65,536
  unsigned short* W5s = (unsigned short*)(ws + 180793232);    // 32,768
  unsigned short* W6s = (unsigned short*)(ws + 180826000);    // 16,384
  int*   btot  = (int*)  (ws + 180842896);                    // 3,128
  int*   bptr  = (int*)  (ws + 180846032);                    // 3,132
  int*   cnt   = (int*)  (ws + 180849184);                    // 782*782*4 = 2,446,096

  hipMemsetAsync(btot, 0, NBK*4, stream);

  // scan-based multi-split CSR build (no high-contention atomics)
  hist2_k <<<EBLK, 256, 0, stream>>>(ei, cnt, btot);
  bscan2_k<<<1, 1024, 0, stream>>>(btot, bptr);
  bkpfx_k <<<NBK, 256, 0, stream>>>(cnt, bptr);
  scat2_k <<<EBLK, 256, 0, stream>>>(ei, cnt, ebuf);
  bcsr_k  <<<NBK, 256, 0, stream>>>(ebuf, bptr, rp, dinv, col);

  wswz_all_k<<<dim3(32,6), 256, 0, stream>>>(W1,W2,W3,W4,W5,W6, W1s,W2s,W3s,W4s,W5s,W6s);
  f2q_k<<<(NN*128/4 + 255)/256, 256, 0, stream>>>(x, xq, NN*128/4);

  // sliced spmm grids: 64 rows/block, NRB=1563 row-blocks; 8/SLICES XCDs per slice
  const int NRB = (NN + 63)/64;
  const int G4 = 8 * ((NRB + 1)/2);   // SLICES=4 (C=256)
  const int G2 = 8 * ((NRB + 3)/4);   // SLICES=2 (C=128)
  const int G1 = 8 * ((NRB + 7)/8);   // SLICES=1 (C=64)
  const int GB2 = (NN + 127)/128;

  // L1: aggregate-first at width 128 (Â x, fp8 gather), then GEMM 128->256 (+b1, relu, bf16)
  spmms_k<128,2,true,false,false><<<G2,256,0,stream>>>(xq, hA, rp, col, dinv, nullptr);
  mgemm_k<128,256,0><<<GB2,256,0,stream>>>(hA, W1s, b1, hB, nullptr, NN);
  // L2: GEMM (*dinv -> fp8), spmm fp8 gather (+b2, relu -> bf16)
  mgemm_k<256,256,1><<<GB2,256,0,stream>>>(hB, W2s, dinv, nullptr, hQ, NN);
  spmms_k<256,4,false,true,true><<<G4,256,0,stream>>>(hQ, hA, rp, col, dinv, b2);
  // L3
  mgemm_k<256,256,1><<<GB2,256,0,stream>>>(hA, W3s, dinv, nullptr, hQ, NN);
  spmms_k<256,4,false,true,true><<<G4,256,0,stream>>>(hQ, hB, rp, col, dinv, b3);
  // L4: 256->128
  mgemm_k<256,128,1><<<GB2,256,0,stream>>>(hB, W4s, dinv, nullptr, hQ, NN);
  spmms_k<128,2,false,true,true><<<G2,256,0,stream>>>(hQ, hA, rp, col, dinv, b4);
  // L5: 128->128
  mgemm_k<128,128,1><<<GB2,256,0,stream>>>(hA, W5s, dinv, nullptr, hQ, NN);
  spmms_k<128,2,false,true,true><<<G2,256,0,stream>>>(hQ, hB, rp, col, dinv, b5);
  // L6: 128->64, no relu
  mgemm_k<128,64,1><<<GB2,256,0,stream>>>(hB, W6s, dinv, nullptr, hQ, NN);
  spmms_k<64,1,false,false,true><<<G1,256,0,stream>>>(hQ, hA, rp, col, dinv, b6);

  // fused deterministic mean-pool + head
  poolhead_k<<<NG, 256, 0, stream>>>(hA, batch, Wl, bl, out);
}

// Round 10
// 1187.217 us; speedup vs baseline: 1.1684x; 1.1684x over previous
//
#include <hip/hip_runtime.h>
#include <math.h>

#define NN 100000
#define NE 3200000
#define NG 512
#define NBK 782            // dst buckets: ceil(NN/128), bucket = dst>>7
#define EBLK 782           // edge blocks: ceil(NE/4096)

typedef __attribute__((ext_vector_type(8))) short short8;
typedef __attribute__((ext_vector_type(4))) float f32x4;
typedef __attribute__((ext_vector_type(2))) float f32x2;

// ---------------- bf16 / fp8 helpers ----------------
__device__ __forceinline__ float bf2f(unsigned short h){
  return __uint_as_float(((unsigned int)h) << 16);
}
__device__ __forceinline__ unsigned short f2bf(float f){
  unsigned int u = __float_as_uint(f);
  unsigned int r = (u + 0x7fffu + ((u >> 16) & 1u)) >> 16;   // RNE
  return (unsigned short)r;
}
__device__ __forceinline__ void unpack16(uint4 v, float* f){
  f32x2 p;
  p = __builtin_amdgcn_cvt_pk_f32_fp8(v.x, 0); f[0]=p[0];  f[1]=p[1];
  p = __builtin_amdgcn_cvt_pk_f32_fp8(v.x, 1); f[2]=p[0];  f[3]=p[1];
  p = __builtin_amdgcn_cvt_pk_f32_fp8(v.y, 0); f[4]=p[0];  f[5]=p[1];
  p = __builtin_amdgcn_cvt_pk_f32_fp8(v.y, 1); f[6]=p[0];  f[7]=p[1];
  p = __builtin_amdgcn_cvt_pk_f32_fp8(v.z, 0); f[8]=p[0];  f[9]=p[1];
  p = __builtin_amdgcn_cvt_pk_f32_fp8(v.z, 1); f[10]=p[0]; f[11]=p[1];
  p = __builtin_amdgcn_cvt_pk_f32_fp8(v.w, 0); f[12]=p[0]; f[13]=p[1];
  p = __builtin_amdgcn_cvt_pk_f32_fp8(v.w, 1); f[14]=p[0]; f[15]=p[1];
}
__device__ __forceinline__ unsigned char f2fp8(float v){
  int p = __builtin_amdgcn_cvt_pk_fp8_f32(v, v, 0, 0);
  return (unsigned char)p;
}

// ---------------- scan-based multi-split CSR build ----------------
__global__ __launch_bounds__(256) void hist2_k(const int* __restrict__ ei,
    int* __restrict__ cnt, int* __restrict__ btot){
  __shared__ int lh[NBK];
  int t = threadIdx.x, b = blockIdx.x;
  for (int i=t; i<NBK; i+=256) lh[i] = 0;
  __syncthreads();
  int base = b*4096;
  #pragma unroll
  for (int u=0; u<16; u++){
    int e = base + u*256 + t;
    if (e < NE) atomicAdd(&lh[ei[NE + e] >> 7], 1);
  }
  __syncthreads();
  for (int i=t; i<NBK; i+=256){
    int v = lh[i];
    cnt[b*NBK + i] = v;
    if (v) atomicAdd(&btot[i], v);
  }
}
__global__ void bscan2_k(const int* __restrict__ btot, int* __restrict__ bptr){
  __shared__ int sc[1024];
  int t = threadIdx.x;
  int v = (t < NBK) ? btot[t] : 0;
  sc[t] = v; __syncthreads();
  for (int off=1; off<1024; off<<=1){
    int u = (t>=off) ? sc[t-off] : 0;
    __syncthreads(); sc[t] += u; __syncthreads();
  }
  if (t < NBK) bptr[t] = sc[t] - v;
  if (t == 1023) bptr[NBK] = sc[1023];
}
__global__ __launch_bounds__(256) void bkpfx_k(int* __restrict__ cnt, const int* __restrict__ bptr){
  __shared__ int sc[256];
  int b = blockIdx.x, t = threadIdx.x;
  int carry = bptr[b];
  for (int base=0; base<EBLK; base+=256){
    int blk = base + t;
    int v = (blk < EBLK) ? cnt[blk*NBK + b] : 0;
    sc[t] = v; __syncthreads();
    for (int off=1; off<256; off<<=1){
      int u = (t>=off) ? sc[t-off] : 0;
      __syncthreads(); sc[t] += u; __syncthreads();
    }
    if (blk < EBLK) cnt[blk*NBK + b] = carry + sc[t] - v;   // exclusive + base
    carry += sc[255];
    __syncthreads();
  }
}
__global__ __launch_bounds__(256) void scat2_k(const int* __restrict__ ei,
    const int* __restrict__ cnt, uint2* __restrict__ ebuf){
  __shared__ int lh[NBK];
  __shared__ int lo[NBK];
  int t = threadIdx.x, b = blockIdx.x;
  for (int i=t; i<NBK; i+=256){ lh[i] = 0; lo[i] = cnt[b*NBK + i]; }
  __syncthreads();
  int base = b*4096;
  #pragma unroll
  for (int u=0; u<16; u++){
    int e = base + u*256 + t;
    if (e < NE){
      int s = ei[e], d = ei[NE + e];
      int bk = d >> 7;
      int r = atomicAdd(&lh[bk], 1);
      ebuf[lo[bk] + r] = make_uint2((unsigned)s, (unsigned)d);
    }
  }
}
// fused per-bucket CSR finalize: deg count + in-bucket scan -> rp/dinv, then col fill.
__global__ __launch_bounds__(256) void bcsr_k(const uint2* __restrict__ ebuf,
    const int* __restrict__ bptr, int* __restrict__ rp, float* __restrict__ dinv,
    int* __restrict__ col){
  __shared__ int cnt[128];
  __shared__ int off[128];
  __shared__ int sc[128];
  int b = blockIdx.x, t = threadIdx.x;
  int nbase = b << 7;
  int beg = bptr[b], end = bptr[b+1];
  if (t < 128) cnt[t] = 0;
  __syncthreads();
  for (int e = beg + t; e < end; e += 256)
    atomicAdd(&cnt[(int)ebuf[e].y - nbase], 1);
  __syncthreads();
  int v = (t < 128) ? cnt[t] : 0;
  if (t < 128) sc[t] = v;
  __syncthreads();
  for (int o2=1; o2<128; o2<<=1){
    int u = (t < 128 && t >= o2) ? sc[t-o2] : 0;
    __syncthreads();
    if (t < 128) sc[t] += u;
    __syncthreads();
  }
  if (t < 128){
    int node = nbase + t;
    if (node < NN){
      int ex = beg + sc[t] - v;
      rp[node] = ex;
      off[t] = ex;
      dinv[node] = rsqrtf((float)(v + 1));
      cnt[t] = 0;
    }
  }
  if (b == ((NN-1) >> 7) && t == 0) rp[NN] = end;
  __syncthreads();
  for (int e = beg + t; e < end; e += 256){
    uint2 sd = ebuf[e];
    int li = (int)sd.y - nbase;
    int pos = off[li] + atomicAdd(&cnt[li], 1);
    col[pos] = (int)sd.x;
  }
}

// fp32 -> fp8 (4 values/thread)
__global__ void f2q_k(const float* __restrict__ in, unsigned char* __restrict__ out, int n4){
  int i = blockIdx.x*256 + threadIdx.x;
  if (i < n4){
    float4 v = ((const float4*)in)[i];
    int p = __builtin_amdgcn_cvt_pk_fp8_f32(v.x, v.y, 0, 0);
    p = __builtin_amdgcn_cvt_pk_fp8_f32(v.z, v.w, p, 1);
    ((unsigned int*)out)[i] = (unsigned int)p;
  }
}
// all 6 weight swizzles in one launch. blockIdx.y selects config.
// chunk idx = ((kt*(N/16)+nt)*4+q)*16 + l  holds B[k=kt*32+q*8+j][n=nt*16+l], j=0..7
__global__ void wswz_all_k(const float* W1, const float* W2, const float* W3,
                           const float* W4, const float* W5, const float* W6,
                           unsigned short* O1, unsigned short* O2, unsigned short* O3,
                           unsigned short* O4, unsigned short* O5, unsigned short* O6){
  int cfg = blockIdx.y;
  int K, N; const float* W; unsigned short* out;
  switch(cfg){
    case 0: K=128; N=256; W=W1; out=O1; break;
    case 1: K=256; N=256; W=W2; out=O2; break;
    case 2: K=256; N=256; W=W3; out=O3; break;
    case 3: K=256; N=128; W=W4; out=O4; break;
    case 4: K=128; N=128; W=W5; out=O5; break;
    default:K=128; N=64;  W=W6; out=O6; break;
  }
  int idx = blockIdx.x*256 + threadIdx.x;
  int total = K*N/8;
  if (idx >= total) return;
  int l = idx & 15;
  int t = idx >> 4; int q = t & 3; t >>= 2;
  int NT = N/16;
  int nt = t % NT, kt = t / NT;
  int kbase = kt*32 + q*8, n = nt*16 + l;
  short8 o;
  #pragma unroll
  for (int j=0;j<8;j++) o[j] = (short)f2bf(W[(size_t)(kbase+j)*N + n]);
  *(short8*)(out + (size_t)idx*8) = o;
}

// ---------------- fp8 SpMM (round-7 form): out[i]=dinv[i]*(sum in[src]+in[i]) [+bias][relu]
template<int C, bool SRC_SCALE, bool RELU, bool HAS_BIAS>
__global__ __launch_bounds__(256) void spmm8_k(const unsigned char* __restrict__ in,
    unsigned short* __restrict__ out,
    const int* __restrict__ rp, const int* __restrict__ col,
    const float* __restrict__ dinv, const float* __restrict__ bias)
{
  constexpr int LPR = C/16;         // lanes per row
  constexpr int RPW = 64/LPR;       // rows per wave
  constexpr int RPB = 4*RPW;        // rows per block
  int tid = threadIdx.x;
  int wv = tid >> 6, lane = tid & 63;
  int sub = lane / LPR, li = lane % LPR;
  int row = blockIdx.x*RPB + wv*RPW + sub;
  if (row >= NN) return;
  int beg = rp[row], end = rp[row+1];
  float di = dinv[row];
  int co = li*16;
  const unsigned char* inb = in + co;
  float acc[16], tmp[16];
  unpack16(*(const uint4*)(inb + (size_t)row*C), acc);   // self loop
  if (SRC_SCALE){
    #pragma unroll
    for (int v=0;v<16;v++) acc[v] *= di;
  }
  int j = beg;
  for (; j+8 <= end; j += 8){
    int s[8]; uint4 v[8]; float wgt[8];
    #pragma unroll
    for (int u=0;u<8;u++) s[u] = col[j+u];
    #pragma unroll
    for (int u=0;u<8;u++) v[u] = *(const uint4*)(inb + (size_t)s[u]*C);
    if (SRC_SCALE){
      #pragma unroll
      for (int u=0;u<8;u++) wgt[u] = dinv[s[u]];
    }
    #pragma unroll
    for (int u=0;u<8;u++){
      unpack16(v[u], tmp);
      float w = SRC_SCALE ? wgt[u] : 1.f;
      #pragma unroll
      for (int vv=0;vv<16;vv++) acc[vv] = fmaf(w, tmp[vv], acc[vv]);
    }
  }
  for (; j < end; j++){
    int ss = col[j];
    uint4 v = *(const uint4*)(inb + (size_t)ss*C);
    float w = SRC_SCALE ? dinv[ss] : 1.f;
    unpack16(v, tmp);
    #pragma unroll
    for (int vv=0;vv<16;vv++) acc[vv] = fmaf(w, tmp[vv], acc[vv]);
  }
  float bb[16];
  if (HAS_BIAS){
    #pragma unroll
    for (int u=0;u<4;u++) *(float4*)&bb[u*4] = *(const float4*)(bias + co + u*4);
  }
  #pragma unroll
  for (int v=0;v<16;v++){
    acc[v] *= di;
    if (HAS_BIAS) acc[v] += bb[v];
    if (RELU) acc[v] = fmaxf(acc[v], 0.f);
  }
  uint4 o0, o1;
  o0.x = (unsigned int)f2bf(acc[0])  | ((unsigned int)f2bf(acc[1])<<16);
  o0.y = (unsigned int)f2bf(acc[2])  | ((unsigned int)f2bf(acc[3])<<16);
  o0.z = (unsigned int)f2bf(acc[4])  | ((unsigned int)f2bf(acc[5])<<16);
  o0.w = (unsigned int)f2bf(acc[6])  | ((unsigned int)f2bf(acc[7])<<16);
  o1.x = (unsigned int)f2bf(acc[8])  | ((unsigned int)f2bf(acc[9])<<16);
  o1.y = (unsigned int)f2bf(acc[10]) | ((unsigned int)f2bf(acc[11])<<16);
  o1.z = (unsigned int)f2bf(acc[12]) | ((unsigned int)f2bf(acc[13])<<16);
  o1.w = (unsigned int)f2bf(acc[14]) | ((unsigned int)f2bf(acc[15])<<16);
  unsigned short* op = out + (size_t)row*C + co;
  *(uint4*)op = o0;
  *(uint4*)(op + 8) = o1;
}

// ---------------- MFMA bf16 GEMM, 4 row-tiles/wave, N-split blocks ----------------
// Block: 4 waves, 256 rows (64/wave), NB columns (grid.y = N/NB).
// Per kt per wave: NT ds_read_b128 feed 4*NT MFMAs (MFMA-bound); A prefetched in regs;
// B double-buffered in LDS. EPI=0: +bias,relu,bf16.  EPI=1: *dinv[row], fp8.
template<int K, int N, int NB, int EPI>
__global__ __launch_bounds__(256) void mgemm_k(const unsigned short* __restrict__ A,
    const unsigned short* __restrict__ Bsw,
    const float* __restrict__ aux, unsigned short* __restrict__ Cb,
    unsigned char* __restrict__ Cq, int M)
{
  constexpr int NT = NB/16, KT = K/32;
  constexpr int KSTRIDE = (N/16)*64;      // short8 units per kt-chunk in Bsw
  __shared__ short8 Bl[2][NT*64];
  int tid = threadIdx.x;
  int w = tid >> 6, lane = tid & 63;
  int l = lane & 15, q = lane >> 4;
  int nb0 = blockIdx.y * NB;
  int rb = blockIdx.x*256 + w*64;
  const unsigned short* ap[4];
  #pragma unroll
  for (int rt=0; rt<4; rt++){
    int r = min(rb + rt*16 + l, M-1);
    ap[rt] = A + (size_t)r*K + q*8;
  }
  f32x4 acc[4][NT];
  #pragma unroll
  for (int rt=0; rt<4; rt++)
    #pragma unroll
    for (int nt=0; nt<NT; nt++) acc[rt][nt] = (f32x4){0,0,0,0};
  const short8* bsrc = (const short8*)Bsw + (size_t)(nb0/16)*64;
  // stage kt=0 B, load kt=0 A
  for (int i=tid; i<NT*64; i+=256) Bl[0][i] = bsrc[i];
  short8 a[4], an[4];
  #pragma unroll
  for (int rt=0; rt<4; rt++) a[rt] = *(const short8*)(ap[rt]);
  for (int kt=0; kt<KT; kt++){
    __syncthreads();
    if (kt+1 < KT){
      const short8* s = bsrc + (size_t)(kt+1)*KSTRIDE;
      for (int i=tid; i<NT*64; i+=256) Bl[(kt+1)&1][i] = s[i];
      #pragma unroll
      for (int rt=0; rt<4; rt++) an[rt] = *(const short8*)(ap[rt] + (kt+1)*32);
    }
    const short8* bl = &Bl[kt&1][0];
    #pragma unroll
    for (int nt=0; nt<NT; nt++){
      short8 bf = bl[nt*64 + q*16 + l];
      acc[0][nt] = __builtin_amdgcn_mfma_f32_16x16x32_bf16(a[0], bf, acc[0][nt], 0,0,0);
      acc[1][nt] = __builtin_amdgcn_mfma_f32_16x16x32_bf16(a[1], bf, acc[1][nt], 0,0,0);
      acc[2][nt] = __builtin_amdgcn_mfma_f32_16x16x32_bf16(a[2], bf, acc[2][nt], 0,0,0);
      acc[3][nt] = __builtin_amdgcn_mfma_f32_16x16x32_bf16(a[3], bf, acc[3][nt], 0,0,0);
    }
    #pragma unroll
    for (int rt=0; rt<4; rt++) a[rt] = an[rt];
  }
  #pragma unroll
  for (int rt=0; rt<4; rt++){
    int rbb = rb + rt*16;
    #pragma unroll
    for (int nt=0; nt<NT; nt++){
      f32x4 av = acc[rt][nt];
      int n = nb0 + nt*16 + l;
      #pragma unroll
      for (int r=0;r<4;r++){
        int row = rbb + q*4 + r;
        if (row < M){
          float v = av[r];
          if (EPI == 0){
            v = fmaxf(v + aux[n], 0.f);
            Cb[(size_t)row*N + n] = f2bf(v);
          } else {
            v *= aux[row];
            Cq[(size_t)row*N + n] = f2fp8(v);
          }
        }
      }
    }
  }
}

// ---------------- fused mean-pool + linear + (log_)softmax (batch sorted) ----------------
__global__ __launch_bounds__(256) void poolhead_k(const unsigned short* __restrict__ h,
    const int* __restrict__ batch, const float* __restrict__ Wlin,
    const float* __restrict__ blin, float* __restrict__ out)
{
  __shared__ int range[2];
  __shared__ float red[4][64];
  __shared__ float pl[64];
  int g = blockIdx.x;
  if (threadIdx.x < 2){
    int target = g + threadIdx.x;      // lower_bound(batch, target)
    int lo = 0, hi = NN;
    while (lo < hi){ int m = (lo+hi) >> 1; if (batch[m] < target) lo = m+1; else hi = m; }
    range[threadIdx.x] = lo;
  }
  __syncthreads();
  int lo = range[0], hi = range[1];
  int ch = threadIdx.x & 63, rg = threadIdx.x >> 6;
  float s = 0.f;
  for (int r = lo + rg; r < hi; r += 4) s += bf2f(h[(size_t)r*64 + ch]);
  red[rg][ch] = s; __syncthreads();
  if (rg == 0){
    float tot = red[0][ch] + red[1][ch] + red[2][ch] + red[3][ch];
    pl[ch] = tot / fmaxf((float)(hi - lo), 1.f);
  }
  __syncthreads();
  if (threadIdx.x == 0){
    float l[10];
    #pragma unroll
    for (int j=0;j<10;j++) l[j] = blin[j];
    for (int c=0;c<64;c++){
      float p = pl[c];
      #pragma unroll
      for (int j=0;j<10;j++) l[j] = fmaf(p, Wlin[c*10 + j], l[j]);
    }
    float mx = l[0];
    #pragma unroll
    for (int j=1;j<10;j++) mx = fmaxf(mx, l[j]);
    float e[10]; float se = 0.f;
    #pragma unroll
    for (int j=0;j<10;j++){ e[j] = expf(l[j]-mx); se += e[j]; }
    float lse = logf(se);
    #pragma unroll
    for (int j=0;j<10;j++){
      out[g*10 + j]         = l[j] - mx - lse;   // log_softmax
      out[NG*10 + g*10 + j] = e[j] / se;         // softmax
    }
  }
}

// ---------------- launch ----------------
extern "C" void kernel_launch(void* const* d_in, const int* in_sizes, int n_in,
                              void* d_out, int out_size, void* d_ws, size_t ws_size,
                              hipStream_t stream)
{
  const float* x     = (const float*)d_in[0];
  const int*   ei    = (const int*)  d_in[1];
  const int*   batch = (const int*)  d_in[2];
  const float* W1=(const float*)d_in[4],  *b1=(const float*)d_in[5];
  const float* W2=(const float*)d_in[6],  *b2=(const float*)d_in[7];
  const float* W3=(const float*)d_in[8],  *b3=(const float*)d_in[9];
  const float* W4=(const float*)d_in[10], *b4=(const float*)d_in[11];
  const float* W5=(const float*)d_in[12], *b5=(const float*)d_in[13];
  const float* W6=(const float*)d_in[14], *b6=(const float*)d_in[15];
  const float* Wl=(const float*)d_in[16], *bl=(const float*)d_in[17];
  float* out = (float*)d_out;

  char* ws = (char*)d_ws;
  unsigned short* hA  = (unsigned short*)(ws + 0);            // bf16 51,200,000
  unsigned short* hB  = (unsigned short*)(ws + 51200000);     // bf16 51,200,000
  unsigned char*  hQ  = (unsigned char*) (ws + 102400000);    // fp8  25,600,000
  unsigned char*  xq  = (unsigned char*) (ws + 128000000);    // fp8  12,800,000
  int*   col   = (int*)  (ws + 140800000);                    // 12,800,000
  uint2* ebuf  = (uint2*)(ws + 153600000);                    // 25,600,000
  int*   rp    = (int*)  (ws + 179200000);                    // 400,016
  float* dinv  = (float*)(ws + 180000016);                    // 400,000
  unsigned short* W1s = (unsigned short*)(ws + 180400016);    // 65,536
  unsigned short* W2s = (unsigned short*)(ws + 180465552);    // 131,072
  unsigned short* W3s = (unsigned short*)(ws + 180596624);    // 131,072
  unsigned short* W4s = (unsigned short*)(ws + 180727696);    // 65,536
  unsigned short* W5s = (unsigned short*)(ws + 180793232);    // 32,768
  unsigned short* W6s = (unsigned short*)(ws + 180826000);    // 16,384
  int*   btot  = (int*)  (ws + 180842896);                    // 3,128
  int*   bptr  = (int*)  (ws + 180846032);                    // 3,132
  int*   cnt   = (int*)  (ws + 180849184);                    // 782*782*4 = 2,446,096

  hipMemsetAsync(btot, 0, NBK*4, stream);

  // scan-based multi-split CSR build (no high-contention atomics)
  hist2_k <<<EBLK, 256, 0, stream>>>(ei, cnt, btot);
  bscan2_k<<<1, 1024, 0, stream>>>(btot, bptr);
  bkpfx_k <<<NBK, 256, 0, stream>>>(cnt, bptr);
  scat2_k <<<EBLK, 256, 0, stream>>>(ei, cnt, ebuf);
  bcsr_k  <<<NBK, 256, 0, stream>>>(ebuf, bptr, rp, dinv, col);

  wswz_all_k<<<dim3(32,6), 256, 0, stream>>>(W1,W2,W3,W4,W5,W6, W1s,W2s,W3s,W4s,W5s,W6s);
  f2q_k<<<(NN*128/4 + 255)/256, 256, 0, stream>>>(x, xq, NN*128/4);

  const int SQ256 = (NN + 15)/16, SQ128 = (NN + 31)/32, SQ64 = (NN + 63)/64;
  const int GX = (NN + 255)/256;   // gemm row-blocks (256 rows each)

  // L1: aggregate-first at width 128 (Â x, fp8 gather), then GEMM 128->256 (+b1, relu, bf16)
  spmm8_k<128,true,false,false><<<SQ128,256,0,stream>>>(xq, hA, rp, col, dinv, nullptr);
  mgemm_k<128,256,128,0><<<dim3(GX,2),256,0,stream>>>(hA, W1s, b1, hB, nullptr, NN);
  // L2: GEMM (*dinv -> fp8), spmm fp8 gather (+b2, relu -> bf16)
  mgemm_k<256,256,128,1><<<dim3(GX,2),256,0,stream>>>(hB, W2s, dinv, nullptr, hQ, NN);
  spmm8_k<256,false,true,true><<<SQ256,256,0,stream>>>(hQ, hA, rp, col, dinv, b2);
  // L3
  mgemm_k<256,256,128,1><<<dim3(GX,2),256,0,stream>>>(hA, W3s, dinv, nullptr, hQ, NN);
  spmm8_k<256,false,true,true><<<SQ256,256,0,stream>>>(hQ, hB, rp, col, dinv, b3);
  // L4: 256->128
  mgemm_k<256,128,128,1><<<dim3(GX,1),256,0,stream>>>(hB, W4s, dinv, nullptr, hQ, NN);
  spmm8_k<128,false,true,true><<<SQ128,256,0,stream>>>(hQ, hA, rp, col, dinv, b4);
  // L5: 128->128
  mgemm_k<128,128,128,1><<<dim3(GX,1),256,0,stream>>>(hA, W5s, dinv, nullptr, hQ, NN);
  spmm8_k<128,false,true,true><<<SQ128,256,0,stream>>>(hQ, hB, rp, col, dinv, b5);
  // L6: 128->64, no relu
  mgemm_k<128,64,64,1><<<dim3(GX,1),256,0,stream>>>(hB, W6s, dinv, nullptr, hQ, NN);
  spmm8_k<64,false,false,true><<<SQ64,256,0,stream>>>(hQ, hA, rp, col, dinv, b6);

  // fused deterministic mean-pool + head
  poolhead_k<<<NG, 256, 0, stream>>>(hA, batch, Wl, bl, out);
}

// Round 11
// 1104.024 us; speedup vs baseline: 1.2565x; 1.0754x over previous
//
#include <hip/hip_runtime.h>
#include <math.h>

#define NN 100000
#define NE 3200000
#define NG 512
#define NBK 782            // dst buckets: ceil(NN/128), bucket = dst>>7
#define EBLK 782           // edge blocks: ceil(NE/4096)

typedef __attribute__((ext_vector_type(8))) short short8;
typedef __attribute__((ext_vector_type(4))) float f32x4;
typedef __attribute__((ext_vector_type(2))) float f32x2;

// ---------------- bf16 / fp8 helpers ----------------
__device__ __forceinline__ float bf2f(unsigned short h){
  return __uint_as_float(((unsigned int)h) << 16);
}
__device__ __forceinline__ unsigned short f2bf(float f){
  unsigned int u = __float_as_uint(f);
  unsigned int r = (u + 0x7fffu + ((u >> 16) & 1u)) >> 16;   // RNE
  return (unsigned short)r;
}
__device__ __forceinline__ void unpack16(uint4 v, float* f){
  f32x2 p;
  p = __builtin_amdgcn_cvt_pk_f32_fp8(v.x, 0); f[0]=p[0];  f[1]=p[1];
  p = __builtin_amdgcn_cvt_pk_f32_fp8(v.x, 1); f[2]=p[0];  f[3]=p[1];
  p = __builtin_amdgcn_cvt_pk_f32_fp8(v.y, 0); f[4]=p[0];  f[5]=p[1];
  p = __builtin_amdgcn_cvt_pk_f32_fp8(v.y, 1); f[6]=p[0];  f[7]=p[1];
  p = __builtin_amdgcn_cvt_pk_f32_fp8(v.z, 0); f[8]=p[0];  f[9]=p[1];
  p = __builtin_amdgcn_cvt_pk_f32_fp8(v.z, 1); f[10]=p[0]; f[11]=p[1];
  p = __builtin_amdgcn_cvt_pk_f32_fp8(v.w, 0); f[12]=p[0]; f[13]=p[1];
  p = __builtin_amdgcn_cvt_pk_f32_fp8(v.w, 1); f[14]=p[0]; f[15]=p[1];
}
__device__ __forceinline__ unsigned char f2fp8(float v){
  int p = __builtin_amdgcn_cvt_pk_fp8_f32(v, v, 0, 0);
  return (unsigned char)p;
}

// ---------------- scan-based multi-split CSR build ----------------
__global__ __launch_bounds__(256) void hist2_k(const int* __restrict__ ei,
    int* __restrict__ cnt, int* __restrict__ btot){
  __shared__ int lh[NBK];
  int t = threadIdx.x, b = blockIdx.x;
  for (int i=t; i<NBK; i+=256) lh[i] = 0;
  __syncthreads();
  int base = b*4096;
  #pragma unroll
  for (int u=0; u<16; u++){
    int e = base + u*256 + t;
    if (e < NE) atomicAdd(&lh[ei[NE + e] >> 7], 1);
  }
  __syncthreads();
  for (int i=t; i<NBK; i+=256){
    int v = lh[i];
    cnt[b*NBK + i] = v;
    if (v) atomicAdd(&btot[i], v);
  }
}
__global__ void bscan2_k(const int* __restrict__ btot, int* __restrict__ bptr){
  __shared__ int sc[1024];
  int t = threadIdx.x;
  int v = (t < NBK) ? btot[t] : 0;
  sc[t] = v; __syncthreads();
  for (int off=1; off<1024; off<<=1){
    int u = (t>=off) ? sc[t-off] : 0;
    __syncthreads(); sc[t] += u; __syncthreads();
  }
  if (t < NBK) bptr[t] = sc[t] - v;
  if (t == 1023) bptr[NBK] = sc[1023];
}
__global__ __launch_bounds__(256) void bkpfx_k(int* __restrict__ cnt, const int* __restrict__ bptr){
  __shared__ int sc[256];
  int b = blockIdx.x, t = threadIdx.x;
  int carry = bptr[b];
  for (int base=0; base<EBLK; base+=256){
    int blk = base + t;
    int v = (blk < EBLK) ? cnt[blk*NBK + b] : 0;
    sc[t] = v; __syncthreads();
    for (int off=1; off<256; off<<=1){
      int u = (t>=off) ? sc[t-off] : 0;
      __syncthreads(); sc[t] += u; __syncthreads();
    }
    if (blk < EBLK) cnt[blk*NBK + b] = carry + sc[t] - v;   // exclusive + base
    carry += sc[255];
    __syncthreads();
  }
}
__global__ __launch_bounds__(256) void scat2_k(const int* __restrict__ ei,
    const int* __restrict__ cnt, uint2* __restrict__ ebuf){
  __shared__ int lh[NBK];
  __shared__ int lo[NBK];
  int t = threadIdx.x, b = blockIdx.x;
  for (int i=t; i<NBK; i+=256){ lh[i] = 0; lo[i] = cnt[b*NBK + i]; }
  __syncthreads();
  int base = b*4096;
  #pragma unroll
  for (int u=0; u<16; u++){
    int e = base + u*256 + t;
    if (e < NE){
      int s = ei[e], d = ei[NE + e];
      int bk = d >> 7;
      int r = atomicAdd(&lh[bk], 1);
      ebuf[lo[bk] + r] = make_uint2((unsigned)s, (unsigned)d);
    }
  }
}
// fused per-bucket CSR finalize: deg count + in-bucket scan -> rp/dinv, then col fill.
__global__ __launch_bounds__(256) void bcsr_k(const uint2* __restrict__ ebuf,
    const int* __restrict__ bptr, int* __restrict__ rp, float* __restrict__ dinv,
    int* __restrict__ col){
  __shared__ int cnt[128];
  __shared__ int off[128];
  __shared__ int sc[128];
  int b = blockIdx.x, t = threadIdx.x;
  int nbase = b << 7;
  int beg = bptr[b], end = bptr[b+1];
  if (t < 128) cnt[t] = 0;
  __syncthreads();
  for (int e = beg + t; e < end; e += 256)
    atomicAdd(&cnt[(int)ebuf[e].y - nbase], 1);
  __syncthreads();
  int v = (t < 128) ? cnt[t] : 0;
  if (t < 128) sc[t] = v;
  __syncthreads();
  for (int o2=1; o2<128; o2<<=1){
    int u = (t < 128 && t >= o2) ? sc[t-o2] : 0;
    __syncthreads();
    if (t < 128) sc[t] += u;
    __syncthreads();
  }
  if (t < 128){
    int node = nbase + t;
    if (node < NN){
      int ex = beg + sc[t] - v;
      rp[node] = ex;
      off[t] = ex;
      dinv[node] = rsqrtf((float)(v + 1));
      cnt[t] = 0;
    }
  }
  if (b == ((NN-1) >> 7) && t == 0) rp[NN] = end;
  __syncthreads();
  for (int e = beg + t; e < end; e += 256){
    uint2 sd = ebuf[e];
    int li = (int)sd.y - nbase;
    int pos = off[li] + atomicAdd(&cnt[li], 1);
    col[pos] = (int)sd.x;
  }
}

// fp32 -> fp8 (4 values/thread)
__global__ void f2q_k(const float* __restrict__ in, unsigned char* __restrict__ out, int n4){
  int i = blockIdx.x*256 + threadIdx.x;
  if (i < n4){
    float4 v = ((const float4*)in)[i];
    int p = __builtin_amdgcn_cvt_pk_fp8_f32(v.x, v.y, 0, 0);
    p = __builtin_amdgcn_cvt_pk_fp8_f32(v.z, v.w, p, 1);
    ((unsigned int*)out)[i] = (unsigned int)p;
  }
}
// all 6 weight swizzles in one launch. blockIdx.y selects config.
// chunk idx = ((kt*(N/16)+nt)*4+q)*16 + l  holds B[k=kt*32+q*8+j][n=nt*16+l], j=0..7
__global__ void wswz_all_k(const float* W1, const float* W2, const float* W3,
                           const float* W4, const float* W5, const float* W6,
                           unsigned short* O1, unsigned short* O2, unsigned short* O3,
                           unsigned short* O4, unsigned short* O5, unsigned short* O6){
  int cfg = blockIdx.y;
  int K, N; const float* W; unsigned short* out;
  switch(cfg){
    case 0: K=128; N=256; W=W1; out=O1; break;
    case 1: K=256; N=256; W=W2; out=O2; break;
    case 2: K=256; N=256; W=W3; out=O3; break;
    case 3: K=256; N=128; W=W4; out=O4; break;
    case 4: K=128; N=128; W=W5; out=O5; break;
    default:K=128; N=64;  W=W6; out=O6; break;
  }
  int idx = blockIdx.x*256 + threadIdx.x;
  int total = K*N/8;
  if (idx >= total) return;
  int l = idx & 15;
  int t = idx >> 4; int q = t & 3; t >>= 2;
  int NT = N/16;
  int nt = t % NT, kt = t / NT;
  int kbase = kt*32 + q*8, n = nt*16 + l;
  short8 o;
  #pragma unroll
  for (int j=0;j<8;j++) o[j] = (short)f2bf(W[(size_t)(kbase+j)*N + n]);
  *(short8*)(out + (size_t)idx*8) = o;
}

// ---------------- fp8 SpMM (round-7 form): out[i]=dinv[i]*(sum in[src]+in[i]) [+bias][relu]
template<int C, bool SRC_SCALE, bool RELU, bool HAS_BIAS>
__global__ __launch_bounds__(256) void spmm8_k(const unsigned char* __restrict__ in,
    unsigned short* __restrict__ out,
    const int* __restrict__ rp, const int* __restrict__ col,
    const float* __restrict__ dinv, const float* __restrict__ bias)
{
  constexpr int LPR = C/16;         // lanes per row
  constexpr int RPW = 64/LPR;       // rows per wave
  constexpr int RPB = 4*RPW;        // rows per block
  int tid = threadIdx.x;
  int wv = tid >> 6, lane = tid & 63;
  int sub = lane / LPR, li = lane % LPR;
  int row = blockIdx.x*RPB + wv*RPW + sub;
  if (row >= NN) return;
  int beg = rp[row], end = rp[row+1];
  float di = dinv[row];
  int co = li*16;
  const unsigned char* inb = in + co;
  float acc[16], tmp[16];
  unpack16(*(const uint4*)(inb + (size_t)row*C), acc);   // self loop
  if (SRC_SCALE){
    #pragma unroll
    for (int v=0;v<16;v++) acc[v] *= di;
  }
  int j = beg;
  for (; j+8 <= end; j += 8){
    int s[8]; uint4 v[8]; float wgt[8];
    #pragma unroll
    for (int u=0;u<8;u++) s[u] = col[j+u];
    #pragma unroll
    for (int u=0;u<8;u++) v[u] = *(const uint4*)(inb + (size_t)s[u]*C);
    if (SRC_SCALE){
      #pragma unroll
      for (int u=0;u<8;u++) wgt[u] = dinv[s[u]];
    }
    #pragma unroll
    for (int u=0;u<8;u++){
      unpack16(v[u], tmp);
      float w = SRC_SCALE ? wgt[u] : 1.f;
      #pragma unroll
      for (int vv=0;vv<16;vv++) acc[vv] = fmaf(w, tmp[vv], acc[vv]);
    }
  }
  for (; j < end; j++){
    int ss = col[j];
    uint4 v = *(const uint4*)(inb + (size_t)ss*C);
    float w = SRC_SCALE ? dinv[ss] : 1.f;
    unpack16(v, tmp);
    #pragma unroll
    for (int vv=0;vv<16;vv++) acc[vv] = fmaf(w, tmp[vv], acc[vv]);
  }
  float bb[16];
  if (HAS_BIAS){
    #pragma unroll
    for (int u=0;u<4;u++) *(float4*)&bb[u*4] = *(const float4*)(bias + co + u*4);
  }
  #pragma unroll
  for (int v=0;v<16;v++){
    acc[v] *= di;
    if (HAS_BIAS) acc[v] += bb[v];
    if (RELU) acc[v] = fmaxf(acc[v], 0.f);
  }
  uint4 o0, o1;
  o0.x = (unsigned int)f2bf(acc[0])  | ((unsigned int)f2bf(acc[1])<<16);
  o0.y = (unsigned int)f2bf(acc[2])  | ((unsigned int)f2bf(acc[3])<<16);
  o0.z = (unsigned int)f2bf(acc[4])  | ((unsigned int)f2bf(acc[5])<<16);
  o0.w = (unsigned int)f2bf(acc[6])  | ((unsigned int)f2bf(acc[7])<<16);
  o1.x = (unsigned int)f2bf(acc[8])  | ((unsigned int)f2bf(acc[9])<<16);
  o1.y = (unsigned int)f2bf(acc[10]) | ((unsigned int)f2bf(acc[11])<<16);
  o1.z = (unsigned int)f2bf(acc[12]) | ((unsigned int)f2bf(acc[13])<<16);
  o1.w = (unsigned int)f2bf(acc[14]) | ((unsigned int)f2bf(acc[15])<<16);
  unsigned short* op = out + (size_t)row*C + co;
  *(uint4*)op = o0;
  *(uint4*)(op + 8) = o1;
}

// ---------------- MFMA bf16 GEMM, stage-once B slice, barrier-free K-loop ----------------
// Block: 4 waves, 256 rows, NB=64 cols (grid.y = N/64). Whole K x 64 B-slice (<=32KB)
// staged in LDS ONCE (single barrier), then waves run the K-loop independently:
// per kt per wave: 4 ds_read_b128 + 4 prefetched A loads + 16 MFMAs.
// acc[4][4] = 64 VGPRs keeps occupancy healthy (vs r10's 128+ -> collapse).
// EPI=0: +bias,relu,bf16.  EPI=1: *dinv[row], fp8.
template<int K, int N, int EPI>
__global__ __launch_bounds__(256) void mgemm_k(const unsigned short* __restrict__ A,
    const unsigned short* __restrict__ Bsw,
    const float* __restrict__ aux, unsigned short* __restrict__ Cb,
    unsigned char* __restrict__ Cq, int M)
{
  constexpr int NT = 4;                   // 64 cols = 4 n-tiles
  constexpr int KT = K/32;
  constexpr int NTF = N/16;               // n-tiles in full Bsw
  __shared__ short8 Bl[KT*NT*64];         // K x 64 slice: KT*4*64 short8 = K*64*2 B
  int tid = threadIdx.x;
  int w = tid >> 6, lane = tid & 63;
  int l = lane & 15, q = lane >> 4;
  int nb0 = blockIdx.y * 64;
  int rb = blockIdx.x*256 + w*64;
  // stage whole B slice (one barrier)
  {
    const short8* bsrc = (const short8*)Bsw;
    for (int i = tid; i < KT*NT*64; i += 256){
      int kt = i >> 8;                    // /(NT*64)
      int rem = i & 255;
      Bl[i] = bsrc[(kt*NTF + (nb0 >> 4))*64 + rem];
    }
  }
  const unsigned short* ap[4];
  #pragma unroll
  for (int rt=0; rt<4; rt++){
    int r = min(rb + rt*16 + l, M-1);
    ap[rt] = A + (size_t)r*K + q*8;
  }
  f32x4 acc[4][NT];
  #pragma unroll
  for (int rt=0; rt<4; rt++)
    #pragma unroll
    for (int nt=0; nt<NT; nt++) acc[rt][nt] = (f32x4){0,0,0,0};
  short8 a[4], an[4];
  #pragma unroll
  for (int rt=0; rt<4; rt++) a[rt] = *(const short8*)(ap[rt]);
  __syncthreads();
  for (int kt=0; kt<KT; kt++){
    if (kt+1 < KT){
      #pragma unroll
      for (int rt=0; rt<4; rt++) an[rt] = *(const short8*)(ap[rt] + (kt+1)*32);
    }
    const short8* bl = &Bl[kt << 8];
    #pragma unroll
    for (int nt=0; nt<NT; nt++){
      short8 bf = bl[nt*64 + q*16 + l];
      acc[0][nt] = __builtin_amdgcn_mfma_f32_16x16x32_bf16(a[0], bf, acc[0][nt], 0,0,0);
      acc[1][nt] = __builtin_amdgcn_mfma_f32_16x16x32_bf16(a[1], bf, acc[1][nt], 0,0,0);
      acc[2][nt] = __builtin_amdgcn_mfma_f32_16x16x32_bf16(a[2], bf, acc[2][nt], 0,0,0);
      acc[3][nt] = __builtin_amdgcn_mfma_f32_16x16x32_bf16(a[3], bf, acc[3][nt], 0,0,0);
    }
    #pragma unroll
    for (int rt=0; rt<4; rt++) a[rt] = an[rt];
  }
  #pragma unroll
  for (int rt=0; rt<4; rt++){
    int rbb = rb + rt*16;
    #pragma unroll
    for (int nt=0; nt<NT; nt++){
      f32x4 av = acc[rt][nt];
      int n = nb0 + nt*16 + l;
      #pragma unroll
      for (int r=0;r<4;r++){
        int row = rbb + q*4 + r;
        if (row < M){
          float v = av[r];
          if (EPI == 0){
            v = fmaxf(v + aux[n], 0.f);
            Cb[(size_t)row*N + n] = f2bf(v);
          } else {
            v *= aux[row];
            Cq[(size_t)row*N + n] = f2fp8(v);
          }
        }
      }
    }
  }
}

// ---------------- fused mean-pool + linear + (log_)softmax (batch sorted) ----------------
__global__ __launch_bounds__(256) void poolhead_k(const unsigned short* __restrict__ h,
    const int* __restrict__ batch, const float* __restrict__ Wlin,
    const float* __restrict__ blin, float* __restrict__ out)
{
  __shared__ int range[2];
  __shared__ float red[4][64];
  __shared__ float pl[64];
  int g = blockIdx.x;
  if (threadIdx.x < 2){
    int target = g + threadIdx.x;      // lower_bound(batch, target)
    int lo = 0, hi = NN;
    while (lo < hi){ int m = (lo+hi) >> 1; if (batch[m] < target) lo = m+1; else hi = m; }
    range[threadIdx.x] = lo;
  }
  __syncthreads();
  int lo = range[0], hi = range[1];
  int ch = threadIdx.x & 63, rg = threadIdx.x >> 6;
  float s = 0.f;
  for (int r = lo + rg; r < hi; r += 4) s += bf2f(h[(size_t)r*64 + ch]);
  red[rg][ch] = s; __syncthreads();
  if (rg == 0){
    float tot = red[0][ch] + red[1][ch] + red[2][ch] + red[3][ch];
    pl[ch] = tot / fmaxf((float)(hi - lo), 1.f);
  }
  __syncthreads();
  if (threadIdx.x == 0){
    float l[10];
    #pragma unroll
    for (int j=0;j<10;j++) l[j] = blin[j];
    for (int c=0;c<64;c++){
      float p = pl[c];
      #pragma unroll
      for (int j=0;j<10;j++) l[j] = fmaf(p, Wlin[c*10 + j], l[j]);
    }
    float mx = l[0];
    #pragma unroll
    for (int j=1;j<10;j++) mx = fmaxf(mx, l[j]);
    float e[10]; float se = 0.f;
    #pragma unroll
    for (int j=0;j<10;j++){ e[j] = expf(l[j]-mx); se += e[j]; }
    float lse = logf(se);
    #pragma unroll
    for (int j=0;j<10;j++){
      out[g*10 + j]         = l[j] - mx - lse;   // log_softmax
      out[NG*10 + g*10 + j] = e[j] / se;         // softmax
    }
  }
}

// ---------------- launch ----------------
extern "C" void kernel_launch(void* const* d_in, const int* in_sizes, int n_in,
                              void* d_out, int out_size, void* d_ws, size_t ws_size,
                              hipStream_t stream)
{
  const float* x     = (const float*)d_in[0];
  const int*   ei    = (const int*)  d_in[1];
  const int*   batch = (const int*)  d_in[2];
  const float* W1=(const float*)d_in[4],  *b1=(const float*)d_in[5];
  const float* W2=(const float*)d_in[6],  *b2=(const float*)d_in[7];
  const float* W3=(const float*)d_in[8],  *b3=(const float*)d_in[9];
  const float* W4=(const float*)d_in[10], *b4=(const float*)d_in[11];
  const float* W5=(const float*)d_in[12], *b5=(const float*)d_in[13];
  const float* W6=(const float*)d_in[14], *b6=(const float*)d_in[15];
  const float* Wl=(const float*)d_in[16], *bl=(const float*)d_in[17];
  float* out = (float*)d_out;

  char* ws = (char*)d_ws;
  unsigned short* hA  = (unsigned short*)(ws + 0);            // bf16 51,200,000
  unsigned short* hB  = (unsigned short*)(ws + 51200000);     // bf16 51,200,000
  unsigned char*  hQ  = (unsigned char*) (ws + 102400000);    // fp8  25,600,000
  unsigned char*  xq  = (unsigned char*) (ws + 128000000);    // fp8  12,800,000
  int*   col   = (int*)  (ws + 140800000);                    // 12,800,000
  uint2* ebuf  = (uint2*)(ws + 153600000);                    // 25,600,000
  int*   rp    = (int*)  (ws + 179200000);                    // 400,016
  float* dinv  = (float*)(ws + 180000016);                    // 400,000
  unsigned short* W1s = (unsigned short*)(ws + 180400016);    // 65,536
  unsigned short* W2s = (unsigned short*)(ws + 180465552);    // 131,072
  unsigned short* W3s = (unsigned short*)(ws + 180596624);    // 131,072
  unsigned short* W4s = (unsigned short*)(ws + 180727696);    // 65,536
  unsigned short* W5s = (unsigned short*)(ws + 180793232);    // 32,768
  unsigned short* W6s = (unsigned short*)(ws + 180826000);    // 16,384
  int*   btot  = (int*)  (ws + 180842896);                    // 3,128
  int*   bptr  = (int*)  (ws + 180846032);                    // 3,132
  int*   cnt   = (int*)  (ws + 180849184);                    // 782*782*4 = 2,446,096

  hipMemsetAsync(btot, 0, NBK*4, stream);

  // scan-based multi-split CSR build (no high-contention atomics)
  hist2_k <<<EBLK, 256, 0, stream>>>(ei, cnt, btot);
  bscan2_k<<<1, 1024, 0, stream>>>(btot, bptr);
  bkpfx_k <<<NBK, 256, 0, stream>>>(cnt, bptr);
  scat2_k <<<EBLK, 256, 0, stream>>>(ei, cnt, ebuf);
  bcsr_k  <<<NBK, 256, 0, stream>>>(ebuf, bptr, rp, dinv, col);

  wswz_all_k<<<dim3(32,6), 256, 0, stream>>>(W1,W2,W3,W4,W5,W6, W1s,W2s,W3s,W4s,W5s,W6s);
  f2q_k<<<(NN*128/4 + 255)/256, 256, 0, stream>>>(x, xq, NN*128/4);

  const int SQ256 = (NN + 15)/16, SQ128 = (NN + 31)/32, SQ64 = (NN + 63)/64;
  const int GX = (NN + 255)/256;   // gemm row-blocks (256 rows each)

  // L1: aggregate-first at width 128 (Â x, fp8 gather), then GEMM 128->256 (+b1, relu, bf16)
  spmm8_k<128,true,false,false><<<SQ128,256,0,stream>>>(xq, hA, rp, col, dinv, nullptr);
  mgemm_k<128,256,0><<<dim3(GX,4),256,0,stream>>>(hA, W1s, b1, hB, nullptr, NN);
  // L2: GEMM (*dinv -> fp8), spmm fp8 gather (+b2, relu -> bf16)
  mgemm_k<256,256,1><<<dim3(GX,4),256,0,stream>>>(hB, W2s, dinv, nullptr, hQ, NN);
  spmm8_k<256,false,true,true><<<SQ256,256,0,stream>>>(hQ, hA, rp, col, dinv, b2);
  // L3
  mgemm_k<256,256,1><<<dim3(GX,4),256,0,stream>>>(hA, W3s, dinv, nullptr, hQ, NN);
  spmm8_k<256,false,true,true><<<SQ256,256,0,stream>>>(hQ, hB, rp, col, dinv, b3);
  // L4: 256->128
  mgemm_k<256,128,1><<<dim3(GX,2),256,0,stream>>>(hB, W4s, dinv, nullptr, hQ, NN);
  spmm8_k<128,false,true,true><<<SQ128,256,0,stream>>>(hQ, hA, rp, col, dinv, b4);
  // L5: 128->128
  mgemm_k<128,128,1><<<dim3(GX,2),256,0,stream>>>(hA, W5s, dinv, nullptr, hQ, NN);
  spmm8_k<128,false,true,true><<<SQ128,256,0,stream>>>(hQ, hB, rp, col, dinv, b5);
  // L6: 128->64, no relu
  mgemm_k<128,64,1><<<dim3(GX,1),256,0,stream>>>(hB, W6s, dinv, nullptr, hQ, NN);
  spmm8_k<64,false,false,true><<<SQ64,256,0,stream>>>(hQ, hA, rp, col, dinv, b6);

  // fused deterministic mean-pool + head
  poolhead_k<<<NG, 256, 0, stream>>>(hA, batch, Wl, bl, out);
}

// Round 12
// 1089.774 us; speedup vs baseline: 1.2729x; 1.0131x over previous
//
#include <hip/hip_runtime.h>
#include <math.h>

#define NN 100000
#define NE 3200000
#define NG 512
#define NBK 782            // dst buckets: ceil(NN/128), bucket = dst>>7
#define EBLK 782           // edge blocks: ceil(NE/4096)

typedef __attribute__((ext_vector_type(8))) short short8;
typedef __attribute__((ext_vector_type(4))) float f32x4;
typedef __attribute__((ext_vector_type(2))) float f32x2;

// ---------------- bf16 / fp8 helpers ----------------
__device__ __forceinline__ float bf2f(unsigned short h){
  return __uint_as_float(((unsigned int)h) << 16);
}
__device__ __forceinline__ unsigned short f2bf(float f){
  unsigned int u = __float_as_uint(f);
  unsigned int r = (u + 0x7fffu + ((u >> 16) & 1u)) >> 16;   // RNE
  return (unsigned short)r;
}
__device__ __forceinline__ void unpack16(uint4 v, float* f){
  f32x2 p;
  p = __builtin_amdgcn_cvt_pk_f32_fp8(v.x, 0); f[0]=p[0];  f[1]=p[1];
  p = __builtin_amdgcn_cvt_pk_f32_fp8(v.x, 1); f[2]=p[0];  f[3]=p[1];
  p = __builtin_amdgcn_cvt_pk_f32_fp8(v.y, 0); f[4]=p[0];  f[5]=p[1];
  p = __builtin_amdgcn_cvt_pk_f32_fp8(v.y, 1); f[6]=p[0];  f[7]=p[1];
  p = __builtin_amdgcn_cvt_pk_f32_fp8(v.z, 0); f[8]=p[0];  f[9]=p[1];
  p = __builtin_amdgcn_cvt_pk_f32_fp8(v.z, 1); f[10]=p[0]; f[11]=p[1];
  p = __builtin_amdgcn_cvt_pk_f32_fp8(v.w, 0); f[12]=p[0]; f[13]=p[1];
  p = __builtin_amdgcn_cvt_pk_f32_fp8(v.w, 1); f[14]=p[0]; f[15]=p[1];
}
__device__ __forceinline__ unsigned char f2fp8(float v){
  int p = __builtin_amdgcn_cvt_pk_fp8_f32(v, v, 0, 0);
  return (unsigned char)p;
}

// ---------------- scan-based multi-split CSR build ----------------
// ebuf entries are PACKED: src (17 bits) | dst-within-bucket (7 bits) << 17.
__global__ __launch_bounds__(256) void hist2_k(const int* __restrict__ ei,
    int* __restrict__ cnt, int* __restrict__ btot){
  __shared__ int lh[NBK];
  int t = threadIdx.x, b = blockIdx.x;
  for (int i=t; i<NBK; i+=256) lh[i] = 0;
  __syncthreads();
  int base = b*4096;
  #pragma unroll
  for (int u=0; u<16; u++){
    int e = base + u*256 + t;
    if (e < NE) atomicAdd(&lh[ei[NE + e] >> 7], 1);
  }
  __syncthreads();
  for (int i=t; i<NBK; i+=256){
    int v = lh[i];
    cnt[b*NBK + i] = v;
    if (v) atomicAdd(&btot[i], v);
  }
}
__global__ void bscan2_k(const int* __restrict__ btot, int* __restrict__ bptr){
  __shared__ int sc[1024];
  int t = threadIdx.x;
  int v = (t < NBK) ? btot[t] : 0;
  sc[t] = v; __syncthreads();
  for (int off=1; off<1024; off<<=1){
    int u = (t>=off) ? sc[t-off] : 0;
    __syncthreads(); sc[t] += u; __syncthreads();
  }
  if (t < NBK) bptr[t] = sc[t] - v;
  if (t == 1023) bptr[NBK] = sc[1023];
}
__global__ __launch_bounds__(256) void bkpfx_k(int* __restrict__ cnt, const int* __restrict__ bptr){
  __shared__ int sc[256];
  int b = blockIdx.x, t = threadIdx.x;
  int carry = bptr[b];
  for (int base=0; base<EBLK; base+=256){
    int blk = base + t;
    int v = (blk < EBLK) ? cnt[blk*NBK + b] : 0;
    sc[t] = v; __syncthreads();
    for (int off=1; off<256; off<<=1){
      int u = (t>=off) ? sc[t-off] : 0;
      __syncthreads(); sc[t] += u; __syncthreads();
    }
    if (blk < EBLK) cnt[blk*NBK + b] = carry + sc[t] - v;   // exclusive + base
    carry += sc[255];
    __syncthreads();
  }
}
__global__ __launch_bounds__(256) void scat2_k(const int* __restrict__ ei,
    const int* __restrict__ cnt, unsigned int* __restrict__ ebuf){
  __shared__ int lh[NBK];
  __shared__ int lo[NBK];
  int t = threadIdx.x, b = blockIdx.x;
  for (int i=t; i<NBK; i+=256){ lh[i] = 0; lo[i] = cnt[b*NBK + i]; }
  __syncthreads();
  int base = b*4096;
  #pragma unroll
  for (int u=0; u<16; u++){
    int e = base + u*256 + t;
    if (e < NE){
      int s = ei[e], d = ei[NE + e];
      int bk = d >> 7;
      int r = atomicAdd(&lh[bk], 1);
      ebuf[lo[bk] + r] = (unsigned)s | ((unsigned)(d & 127) << 17);
    }
  }
}
// fused per-bucket CSR finalize: deg count + in-bucket scan -> rp/dinv, then col fill.
__global__ __launch_bounds__(256) void bcsr_k(const unsigned int* __restrict__ ebuf,
    const int* __restrict__ bptr, int* __restrict__ rp, float* __restrict__ dinv,
    int* __restrict__ col){
  __shared__ int cnt[128];
  __shared__ int off[128];
  __shared__ int sc[128];
  int b = blockIdx.x, t = threadIdx.x;
  int nbase = b << 7;
  int beg = bptr[b], end = bptr[b+1];
  if (t < 128) cnt[t] = 0;
  __syncthreads();
  for (int e = beg + t; e < end; e += 256)
    atomicAdd(&cnt[ebuf[e] >> 17], 1);
  __syncthreads();
  int v = (t < 128) ? cnt[t] : 0;
  if (t < 128) sc[t] = v;
  __syncthreads();
  for (int o2=1; o2<128; o2<<=1){
    int u = (t < 128 && t >= o2) ? sc[t-o2] : 0;
    __syncthreads();
    if (t < 128) sc[t] += u;
    __syncthreads();
  }
  if (t < 128){
    int node = nbase + t;
    if (node < NN){
      int ex = beg + sc[t] - v;
      rp[node] = ex;
      off[t] = ex;
      dinv[node] = rsqrtf((float)(v + 1));
      cnt[t] = 0;
    }
  }
  if (b == ((NN-1) >> 7) && t == 0) rp[NN] = end;
  __syncthreads();
  for (int e = beg + t; e < end; e += 256){
    unsigned int sd = ebuf[e];
    int li = sd >> 17;
    int pos = off[li] + atomicAdd(&cnt[li], 1);
    col[pos] = (int)(sd & 0x1FFFF);
  }
}

// fp32 -> fp8 (4 values/thread)
__global__ void f2q_k(const float* __restrict__ in, unsigned char* __restrict__ out, int n4){
  int i = blockIdx.x*256 + threadIdx.x;
  if (i < n4){
    float4 v = ((const float4*)in)[i];
    int p = __builtin_amdgcn_cvt_pk_fp8_f32(v.x, v.y, 0, 0);
    p = __builtin_amdgcn_cvt_pk_fp8_f32(v.z, v.w, p, 1);
    ((unsigned int*)out)[i] = (unsigned int)p;
  }
}
// all 6 weight swizzles in one launch. blockIdx.y selects config.
// chunk idx = ((kt*(N/16)+nt)*4+q)*16 + l  holds B[k=kt*32+q*8+j][n=nt*16+l], j=0..7
__global__ void wswz_all_k(const float* W1, const float* W2, const float* W3,
                           const float* W4, const float* W5, const float* W6,
                           unsigned short* O1, unsigned short* O2, unsigned short* O3,
                           unsigned short* O4, unsigned short* O5, unsigned short* O6){
  int cfg = blockIdx.y;
  int K, N; const float* W; unsigned short* out;
  switch(cfg){
    case 0: K=128; N=256; W=W1; out=O1; break;
    case 1: K=256; N=256; W=W2; out=O2; break;
    case 2: K=256; N=256; W=W3; out=O3; break;
    case 3: K=256; N=128; W=W4; out=O4; break;
    case 4: K=128; N=128; W=W5; out=O5; break;
    default:K=128; N=64;  W=W6; out=O6; break;
  }
  int idx = blockIdx.x*256 + threadIdx.x;
  int total = K*N/8;
  if (idx >= total) return;
  int l = idx & 15;
  int t = idx >> 4; int q = t & 3; t >>= 2;
  int NT = N/16;
  int nt = t % NT, kt = t / NT;
  int kbase = kt*32 + q*8, n = nt*16 + l;
  short8 o;
  #pragma unroll
  for (int j=0;j<8;j++) o[j] = (short)f2bf(W[(size_t)(kbase+j)*N + n]);
  *(short8*)(out + (size_t)idx*8) = o;
}

// ---------------- fp8 SpMM (at random-gather HBM roofline — do not touch) ----------------
template<int C, bool SRC_SCALE, bool RELU, bool HAS_BIAS>
__global__ __launch_bounds__(256) void spmm8_k(const unsigned char* __restrict__ in,
    unsigned short* __restrict__ out,
    const int* __restrict__ rp, const int* __restrict__ col,
    const float* __restrict__ dinv, const float* __restrict__ bias)
{
  constexpr int LPR = C/16;         // lanes per row
  constexpr int RPW = 64/LPR;       // rows per wave
  constexpr int RPB = 4*RPW;        // rows per block
  int tid = threadIdx.x;
  int wv = tid >> 6, lane = tid & 63;
  int sub = lane / LPR, li = lane % LPR;
  int row = blockIdx.x*RPB + wv*RPW + sub;
  if (row >= NN) return;
  int beg = rp[row], end = rp[row+1];
  float di = dinv[row];
  int co = li*16;
  const unsigned char* inb = in + co;
  float acc[16], tmp[16];
  unpack16(*(const uint4*)(inb + (size_t)row*C), acc);   // self loop
  if (SRC_SCALE){
    #pragma unroll
    for (int v=0;v<16;v++) acc[v] *= di;
  }
  int j = beg;
  for (; j+8 <= end; j += 8){
    int s[8]; uint4 v[8]; float wgt[8];
    #pragma unroll
    for (int u=0;u<8;u++) s[u] = col[j+u];
    #pragma unroll
    for (int u=0;u<8;u++) v[u] = *(const uint4*)(inb + (size_t)s[u]*C);
    if (SRC_SCALE){
      #pragma unroll
      for (int u=0;u<8;u++) wgt[u] = dinv[s[u]];
    }
    #pragma unroll
    for (int u=0;u<8;u++){
      unpack16(v[u], tmp);
      float w = SRC_SCALE ? wgt[u] : 1.f;
      #pragma unroll
      for (int vv=0;vv<16;vv++) acc[vv] = fmaf(w, tmp[vv], acc[vv]);
    }
  }
  for (; j < end; j++){
    int ss = col[j];
    uint4 v = *(const uint4*)(inb + (size_t)ss*C);
    float w = SRC_SCALE ? dinv[ss] : 1.f;
    unpack16(v, tmp);
    #pragma unroll
    for (int vv=0;vv<16;vv++) acc[vv] = fmaf(w, tmp[vv], acc[vv]);
  }
  float bb[16];
  if (HAS_BIAS){
    #pragma unroll
    for (int u=0;u<4;u++) *(float4*)&bb[u*4] = *(const float4*)(bias + co + u*4);
  }
  #pragma unroll
  for (int v=0;v<16;v++){
    acc[v] *= di;
    if (HAS_BIAS) acc[v] += bb[v];
    if (RELU) acc[v] = fmaxf(acc[v], 0.f);
  }
  uint4 o0, o1;
  o0.x = (unsigned int)f2bf(acc[0])  | ((unsigned int)f2bf(acc[1])<<16);
  o0.y = (unsigned int)f2bf(acc[2])  | ((unsigned int)f2bf(acc[3])<<16);
  o0.z = (unsigned int)f2bf(acc[4])  | ((unsigned int)f2bf(acc[5])<<16);
  o0.w = (unsigned int)f2bf(acc[6])  | ((unsigned int)f2bf(acc[7])<<16);
  o1.x = (unsigned int)f2bf(acc[8])  | ((unsigned int)f2bf(acc[9])<<16);
  o1.y = (unsigned int)f2bf(acc[10]) | ((unsigned int)f2bf(acc[11])<<16);
  o1.z = (unsigned int)f2bf(acc[12]) | ((unsigned int)f2bf(acc[13])<<16);
  o1.w = (unsigned int)f2bf(acc[14]) | ((unsigned int)f2bf(acc[15])<<16);
  unsigned short* op = out + (size_t)row*C + co;
  *(uint4*)op = o0;
  *(uint4*)(op + 8) = o1;
}

// ---------------- MFMA bf16 GEMM, stage-once B slice, barrier-free K-loop ----------------
// Grid = dim3(N/64, GX): col-slices vary FASTEST, so the 4 slices sharing one A row-tile
// run concurrently and A re-reads hit L2/L3 instead of HBM (r11 grid had row fastest ->
// A streamed from HBM N/64 times).
// Block: 4 waves, 256 rows, 64 cols. K x 64 B-slice (<=32KB LDS) staged once, one barrier,
// then a barrier-free K-loop: 4 ds_read_b128 + 4 prefetched A loads + 16 MFMAs per kt/wave.
// EPI=0: +bias,relu,bf16.  EPI=1: *dinv[row], fp8.
template<int K, int N, int EPI>
__global__ __launch_bounds__(256) void mgemm_k(const unsigned short* __restrict__ A,
    const unsigned short* __restrict__ Bsw,
    const float* __restrict__ aux, unsigned short* __restrict__ Cb,
    unsigned char* __restrict__ Cq, int M)
{
  constexpr int NT = 4;                   // 64 cols = 4 n-tiles
  constexpr int KT = K/32;
  constexpr int NTF = N/16;               // n-tiles in full Bsw
  __shared__ short8 Bl[KT*NT*64];         // K x 64 slice: KT*4*64 short8 = K*64*2 B
  int tid = threadIdx.x;
  int w = tid >> 6, lane = tid & 63;
  int l = lane & 15, q = lane >> 4;
  int nb0 = blockIdx.x * 64;              // col slice (fastest)
  int rb = blockIdx.y*256 + w*64;         // row block
  // stage whole B slice (one barrier)
  {
    const short8* bsrc = (const short8*)Bsw;
    for (int i = tid; i < KT*NT*64; i += 256){
      int kt = i >> 8;                    // /(NT*64)
      int rem = i & 255;
      Bl[i] = bsrc[(kt*NTF + (nb0 >> 4))*64 + rem];
    }
  }
  const unsigned short* ap[4];
  #pragma unroll
  for (int rt=0; rt<4; rt++){
    int r = min(rb + rt*16 + l, M-1);
    ap[rt] = A + (size_t)r*K + q*8;
  }
  f32x4 acc[4][NT];
  #pragma unroll
  for (int rt=0; rt<4; rt++)
    #pragma unroll
    for (int nt=0; nt<NT; nt++) acc[rt][nt] = (f32x4){0,0,0,0};
  short8 a[4], an[4];
  #pragma unroll
  for (int rt=0; rt<4; rt++) a[rt] = *(const short8*)(ap[rt]);
  __syncthreads();
  for (int kt=0; kt<KT; kt++){
    if (kt+1 < KT){
      #pragma unroll
      for (int rt=0; rt<4; rt++) an[rt] = *(const short8*)(ap[rt] + (kt+1)*32);
    }
    const short8* bl = &Bl[kt << 8];
    #pragma unroll
    for (int nt=0; nt<NT; nt++){
      short8 bf = bl[nt*64 + q*16 + l];
      acc[0][nt] = __builtin_amdgcn_mfma_f32_16x16x32_bf16(a[0], bf, acc[0][nt], 0,0,0);
      acc[1][nt] = __builtin_amdgcn_mfma_f32_16x16x32_bf16(a[1], bf, acc[1][nt], 0,0,0);
      acc[2][nt] = __builtin_amdgcn_mfma_f32_16x16x32_bf16(a[2], bf, acc[2][nt], 0,0,0);
      acc[3][nt] = __builtin_amdgcn_mfma_f32_16x16x32_bf16(a[3], bf, acc[3][nt], 0,0,0);
    }
    #pragma unroll
    for (int rt=0; rt<4; rt++) a[rt] = an[rt];
  }
  #pragma unroll
  for (int rt=0; rt<4; rt++){
    int rbb = rb + rt*16;
    #pragma unroll
    for (int nt=0; nt<NT; nt++){
      f32x4 av = acc[rt][nt];
      int n = nb0 + nt*16 + l;
      #pragma unroll
      for (int r=0;r<4;r++){
        int row = rbb + q*4 + r;
        if (row < M){
          float v = av[r];
          if (EPI == 0){
            v = fmaxf(v + aux[n], 0.f);
            Cb[(size_t)row*N + n] = f2bf(v);
          } else {
            v *= aux[row];
            Cq[(size_t)row*N + n] = f2fp8(v);
          }
        }
      }
    }
  }
}

// ---------------- fused mean-pool + linear + (log_)softmax (batch sorted) ----------------
__global__ __launch_bounds__(256) void poolhead_k(const unsigned short* __restrict__ h,
    const int* __restrict__ batch, const float* __restrict__ Wlin,
    const float* __restrict__ blin, float* __restrict__ out)
{
  __shared__ int range[2];
  __shared__ float red[4][64];
  __shared__ float pl[64];
  int g = blockIdx.x;
  if (threadIdx.x < 2){
    int target = g + threadIdx.x;      // lower_bound(batch, target)
    int lo = 0, hi = NN;
    while (lo < hi){ int m = (lo+hi) >> 1; if (batch[m] < target) lo = m+1; else hi = m; }
    range[threadIdx.x] = lo;
  }
  __syncthreads();
  int lo = range[0], hi = range[1];
  int ch = threadIdx.x & 63, rg = threadIdx.x >> 6;
  float s = 0.f;
  for (int r = lo + rg; r < hi; r += 4) s += bf2f(h[(size_t)r*64 + ch]);
  red[rg][ch] = s; __syncthreads();
  if (rg == 0){
    float tot = red[0][ch] + red[1][ch] + red[2][ch] + red[3][ch];
    pl[ch] = tot / fmaxf((float)(hi - lo), 1.f);
  }
  __syncthreads();
  if (threadIdx.x == 0){
    float l[10];
    #pragma unroll
    for (int j=0;j<10;j++) l[j] = blin[j];
    for (int c=0;c<64;c++){
      float p = pl[c];
      #pragma unroll
      for (int j=0;j<10;j++) l[j] = fmaf(p, Wlin[c*10 + j], l[j]);
    }
    float mx = l[0];
    #pragma unroll
    for (int j=1;j<10;j++) mx = fmaxf(mx, l[j]);
    float e[10]; float se = 0.f;
    #pragma unroll
    for (int j=0;j<10;j++){ e[j] = expf(l[j]-mx); se += e[j]; }
    float lse = logf(se);
    #pragma unroll
    for (int j=0;j<10;j++){
      out[g*10 + j]         = l[j] - mx - lse;   // log_softmax
      out[NG*10 + g*10 + j] = e[j] / se;         // softmax
    }
  }
}

// ---------------- launch ----------------
extern "C" void kernel_launch(void* const* d_in, const int* in_sizes, int n_in,
                              void* d_out, int out_size, void* d_ws, size_t ws_size,
                              hipStream_t stream)
{
  const float* x     = (const float*)d_in[0];
  const int*   ei    = (const int*)  d_in[1];
  const int*   batch = (const int*)  d_in[2];
  const float* W1=(const float*)d_in[4],  *b1=(const float*)d_in[5];
  const float* W2=(const float*)d_in[6],  *b2=(const float*)d_in[7];
  const float* W3=(const float*)d_in[8],  *b3=(const float*)d_in[9];
  const float* W4=(const float*)d_in[10], *b4=(const float*)d_in[11];
  const float* W5=(const float*)d_in[12], *b5=(const float*)d_in[13];
  const float* W6=(const float*)d_in[14], *b6=(const float*)d_in[15];
  const float* Wl=(const float*)d_in[16], *bl=(const float*)d_in[17];
  float* out = (float*)d_out;

  char* ws = (char*)d_ws;
  unsigned short* hA  = (unsigned short*)(ws + 0);            // bf16 51,200,000
  unsigned short* hB  = (unsigned short*)(ws + 51200000);     // bf16 51,200,000
  unsigned char*  hQ  = (unsigned char*) (ws + 102400000);    // fp8  25,600,000
  unsigned char*  xq  = (unsigned char*) (ws + 128000000);    // fp8  12,800,000
  int*   col   = (int*)  (ws + 140800000);                    // 12,800,000
  unsigned int* ebuf = (unsigned int*)(ws + 153600000);       // 12,800,000 (packed)
  int*   rp    = (int*)  (ws + 166400000);                    // 400,016
  float* dinv  = (float*)(ws + 166800016);                    // 400,000
  unsigned short* W1s = (unsigned short*)(ws + 167200016);    // 65,536
  unsigned short* W2s = (unsigned short*)(ws + 167265552);    // 131,072
  unsigned short* W3s = (unsigned short*)(ws + 167396624);    // 131,072
  unsigned short* W4s = (unsigned short*)(ws + 167527696);    // 65,536
  unsigned short* W5s = (unsigned short*)(ws + 167593232);    // 32,768
  unsigned short* W6s = (unsigned short*)(ws + 167626000);    // 16,384
  int*   btot  = (int*)  (ws + 167642896);                    // 3,128
  int*   bptr  = (int*)  (ws + 167646032);                    // 3,132
  int*   cnt   = (int*)  (ws + 167649184);                    // 782*782*4 = 2,446,096

  hipMemsetAsync(btot, 0, NBK*4, stream);

  // scan-based multi-split CSR build (no high-contention atomics)
  hist2_k <<<EBLK, 256, 0, stream>>>(ei, cnt, btot);
  bscan2_k<<<1, 1024, 0, stream>>>(btot, bptr);
  bkpfx_k <<<NBK, 256, 0, stream>>>(cnt, bptr);
  scat2_k <<<EBLK, 256, 0, stream>>>(ei, cnt, ebuf);
  bcsr_k  <<<NBK, 256, 0, stream>>>(ebuf, bptr, rp, dinv, col);

  wswz_all_k<<<dim3(32,6), 256, 0, stream>>>(W1,W2,W3,W4,W5,W6, W1s,W2s,W3s,W4s,W5s,W6s);
  f2q_k<<<(NN*128/4 + 255)/256, 256, 0, stream>>>(x, xq, NN*128/4);

  const int SQ256 = (NN + 15)/16, SQ128 = (NN + 31)/32, SQ64 = (NN + 63)/64;
  const int GX = (NN + 255)/256;   // gemm row-blocks (256 rows each)

  // L1: aggregate-first at width 128 (Â x, fp8 gather), then GEMM 128->256 (+b1, relu, bf16)
  spmm8_k<128,true,false,false><<<SQ128,256,0,stream>>>(xq, hA, rp, col, dinv, nullptr);
  mgemm_k<128,256,0><<<dim3(4,GX),256,0,stream>>>(hA, W1s, b1, hB, nullptr, NN);
  // L2: GEMM (*dinv -> fp8), spmm fp8 gather (+b2, relu -> bf16)
  mgemm_k<256,256,1><<<dim3(4,GX),256,0,stream>>>(hB, W2s, dinv, nullptr, hQ, NN);
  spmm8_k<256,false,true,true><<<SQ256,256,0,stream>>>(hQ, hA, rp, col, dinv, b2);
  // L3
  mgemm_k<256,256,1><<<dim3(4,GX),256,0,stream>>>(hA, W3s, dinv, nullptr, hQ, NN);
  spmm8_k<256,false,true,true><<<SQ256,256,0,stream>>>(hQ, hB, rp, col, dinv, b3);
  // L4: 256->128
  mgemm_k<256,128,1><<<dim3(2,GX),256,0,stream>>>(hB, W4s, dinv, nullptr, hQ, NN);
  spmm8_k<128,false,true,true><<<SQ128,256,0,stream>>>(hQ, hA, rp, col, dinv, b4);
  // L5: 128->128
  mgemm_k<128,128,1><<<dim3(2,GX),256,0,stream>>>(hA, W5s, dinv, nullptr, hQ, NN);
  spmm8_k<128,false,true,true><<<SQ128,256,0,stream>>>(hQ, hB, rp, col, dinv, b5);
  // L6: 128->64, no relu
  mgemm_k<128,64,1><<<dim3(1,GX),256,0,stream>>>(hB, W6s, dinv, nullptr, hQ, NN);
  spmm8_k<64,false,false,true><<<SQ64,256,0,stream>>>(hQ, hA, rp, col, dinv, b6);

  // fused deterministic mean-pool + head
  poolhead_k<<<NG, 256, 0, stream>>>(hA, batch, Wl, bl, out);
}